// Round 6
// baseline (74.483 us; speedup 1.0000x reference)
//
#include <hip/hip_runtime.h>
#include <math.h>

#define NQ 14
#define NSTATE (1 << NQ)        // 16384
#define DEPTH  6
#define NT     1024             // 16 waves/block

// dword-index swizzle: XOR bits 6-8 into 2-4 (GF(2)-linear)
__device__ __host__ constexpr int swz(int n) { return n ^ ((n >> 4) & 28); }

// fused CNOT ladders (even after odd) — GF(2)-linear
__device__ __host__ constexpr int sigma(int n) {
    int m = n ^ ((n & 0x1554) >> 1);
    return m ^ ((m & 0x2AAA) >> 1);
}

// layout C: pos0-3 = std8-11, pos4-7 = std0-3, pos8-11 = std4-7, pos12-13 = std12-13
__device__ __host__ constexpr int Cmap(int m) {
    return ((m >> 8) & 15) | ((m & 15) << 4) | (((m >> 4) & 15) << 8) | (m & 0x3000);
}

// RY on p-index bit JB over a 16-amp real register block
template <int JB>
__device__ __forceinline__ void ry16(float (&p)[16], float c, float s) {
#pragma unroll
    for (int i = 0; i < 16; ++i) {
        if (!((i >> JB) & 1)) {
            const int i1 = i | (1 << JB);
            float a0 = p[i], a1 = p[i1];
            p[i]  = c * a0 - s * a1;
            p[i1] = s * a0 + c * a1;
        }
    }
}

__device__ __forceinline__ float quad8(const float (&ps)[8],
                                       const float* __restrict__ A,
                                       const float* __restrict__ D, int q) {
    float acc = 0.0f;
#pragma unroll
    for (int i = 0; i < 7; ++i) acc += 2.0f * D[q * 8 + i + 1] * ps[i] * ps[i];
    int kk = 0;
#pragma unroll
    for (int i = 1; i < 8; ++i)
#pragma unroll
        for (int j = 0; j < i; ++j, ++kk)
            acc += 2.0f * A[q * 28 + kk] * ps[i] * ps[j];
    return acc;
}

__global__ __launch_bounds__(NT, 4)
void vqc_kernel(const float* __restrict__ X,    // (512,14)
                const float* __restrict__ TH,   // (6,14)
                const float* __restrict__ A,    // (14,28)
                const float* __restrict__ Bc,   // (14,28) unused: state stays real
                const float* __restrict__ D,    // (14,8)
                float* __restrict__ out)        // (512,2)
{
    __shared__ __align__(16) float st[NSTATE];  // 64 KiB real state
    __shared__ float2 tb[DEPTH * NQ];           // (cos,sin) per theta
    __shared__ float2 xf[NQ];                   // (c-s, c+s) per amplitude bit j
    __shared__ float  red[2 * (NT / 64)];

    const int t = threadIdx.x;
    const int b = blockIdx.x;

    // ---- precompute trig tables (uniform work done once per block) ----
    if (t < DEPTH * NQ) {
        float s, c;
        __sincosf(0.5f * TH[t], &s, &c);
        tb[t] = make_float2(c, s);
    } else if (t < DEPTH * NQ + NQ) {
        const int j = t - DEPTH * NQ;           // amplitude-bit position j <-> wire 13-j
        float s, c;
        __sincosf(0.5f * X[b * NQ + (13 - j)], &s, &c);
        xf[j] = make_float2(c - s, c + s);
    }
    __syncthreads();

    float p[16];

    // ---- layer 0, P1: product-state init evaluated at sigma(n), rotate std0-3 ----
    {
        const int mt = sigma(t << 4);
        float sh = 1.0f / 128.0f;
#pragma unroll
        for (int j = 4; j < 14; ++j) {
            float2 f = xf[j];
            sh *= ((mt >> j) & 1) ? f.y : f.x;
        }
        float fa[4], fb[4];                     // value for bit = mt_j, and flipped
#pragma unroll
        for (int j = 0; j < 4; ++j) {
            float2 f = xf[j];
            const int mj = (mt >> j) & 1;
            fa[j] = mj ? f.y : f.x;
            fb[j] = mj ? f.x : f.y;
        }
#pragma unroll
        for (int i = 0; i < 16; ++i) {
            const int sl = sigma(i);            // compile-time per unrolled i
            float v = sh;
            v *= (sl & 1)        ? fb[0] : fa[0];
            v *= ((sl >> 1) & 1) ? fb[1] : fa[1];
            v *= ((sl >> 2) & 1) ? fb[2] : fa[2];
            v *= ((sl >> 3) & 1) ? fb[3] : fa[3];
            p[i] = v;
        }
        float2 cs;
        cs = tb[13]; ry16<0>(p, cs.x, cs.y);    // std0 <-> wire 13
        cs = tb[12]; ry16<1>(p, cs.x, cs.y);
        cs = tb[11]; ry16<2>(p, cs.x, cs.y);
        cs = tb[10]; ry16<3>(p, cs.x, cs.y);
        const int w0 = swz(t << 4);
#pragma unroll
        for (int g = 0; g < 4; ++g)
            *(float4*)&st[w0 ^ (g << 2)] =
                make_float4(p[4 * g], p[4 * g + 1], p[4 * g + 2], p[4 * g + 3]);
    }
    __syncthreads();

    // ---- layers: P2 (std4-7), P3 (std8-11), P4 (std12-13), then next P1 ----
    for (int k = 0; k < DEPTH; ++k) {
        const float2* tbk = tb + k * NQ;
        float2 cs;

        // P2: read layout A (std), rotate std4-7 (wires 9..6), write layout B
        {
            const int F2 = swz((t & 15) | ((t >> 4) << 8));
#pragma unroll
            for (int i = 0; i < 16; ++i) p[i] = st[F2 ^ swz(i << 4)];
            __syncthreads();
            cs = tbk[9]; ry16<0>(p, cs.x, cs.y);
            cs = tbk[8]; ry16<1>(p, cs.x, cs.y);
            cs = tbk[7]; ry16<2>(p, cs.x, cs.y);
            cs = tbk[6]; ry16<3>(p, cs.x, cs.y);
            const int W2 = swz(((t & 15) << 4) | ((t >> 4) << 8));
#pragma unroll
            for (int g = 0; g < 4; ++g)
                *(float4*)&st[W2 ^ (g << 2)] =
                    make_float4(p[4 * g], p[4 * g + 1], p[4 * g + 2], p[4 * g + 3]);
            __syncthreads();
        }

        // P3: read layout B, rotate std8-11 (wires 5..2), write layout C
        {
            const int F3 = swz(((t >> 4) & 15) | ((t & 15) << 4) | (((t >> 8) & 3) << 12));
#pragma unroll
            for (int i = 0; i < 16; ++i) p[i] = st[F3 ^ swz(i << 8)];
            __syncthreads();
            cs = tbk[5]; ry16<0>(p, cs.x, cs.y);
            cs = tbk[4]; ry16<1>(p, cs.x, cs.y);
            cs = tbk[3]; ry16<2>(p, cs.x, cs.y);
            cs = tbk[2]; ry16<3>(p, cs.x, cs.y);
            const int W3 = swz(((t & 15) << 4) | (((t >> 4) & 15) << 8) | (((t >> 8) & 3) << 12));
#pragma unroll
            for (int g = 0; g < 4; ++g)
                *(float4*)&st[W3 ^ (g << 2)] =
                    make_float4(p[4 * g], p[4 * g + 1], p[4 * g + 2], p[4 * g + 3]);
            __syncthreads();
        }

        // P4: rotate std12-13 (wires 1,0) in layout C, in-place, all b128
        {
            const int B4 = swz(((t & 3) << 2) | (((t >> 2) & 15) << 4) | (((t >> 6) & 15) << 8));
#pragma unroll
            for (int c = 0; c < 4; ++c)
                *(float4*)&p[4 * c] = *(const float4*)&st[B4 ^ (c << 12)];
            cs = tbk[1]; ry16<2>(p, cs.x, cs.y); // p-bit2 = pos12 = std12 = wire 1
            cs = tbk[0]; ry16<3>(p, cs.x, cs.y); // p-bit3 = pos13 = std13 = wire 0
#pragma unroll
            for (int c = 0; c < 4; ++c)
                *(float4*)&st[B4 ^ (c << 12)] = *(const float4*)&p[4 * c];
            __syncthreads();
        }

        // P1 of layer k+1: CNOT gather from layout C, rotate std0-3, write std
        if (k + 1 < DEPTH) {
            const float2* tbn = tb + (k + 1) * NQ;
            const int F1 = swz(Cmap(sigma(t << 4)));
#pragma unroll
            for (int i = 0; i < 16; ++i) p[i] = st[F1 ^ swz(Cmap(sigma(i)))];
            __syncthreads();
            cs = tbn[13]; ry16<0>(p, cs.x, cs.y);
            cs = tbn[12]; ry16<1>(p, cs.x, cs.y);
            cs = tbn[11]; ry16<2>(p, cs.x, cs.y);
            cs = tbn[10]; ry16<3>(p, cs.x, cs.y);
            const int w0 = swz(t << 4);
#pragma unroll
            for (int g = 0; g < 4; ++g)
                *(float4*)&st[w0 ^ (g << 2)] =
                    make_float4(p[4 * g], p[4 * g + 1], p[4 * g + 2], p[4 * g + 3]);
            __syncthreads();
        }
    }

    // ---- expectations from layout C (real state: B drops out) ----
    float e0 = 0.0f, e1 = 0.0f;
#pragma unroll
    for (int half = 0; half < 2; ++half) {
        const int r = t + half * NT;            // 11-bit group id
        // q=0: psi_i, i = std13*4 + std12*2 + std11 -> pos13, pos12, pos3
        {
            const int Fe = swz((r & 7) | (((r >> 3) & 15) << 4) | (((r >> 7) & 15) << 8));
            float ps[8];
#pragma unroll
            for (int i = 0; i < 8; ++i)
                ps[i] = st[Fe ^ ((i & 1) << 3) ^ (((i >> 1) & 1) << 12) ^ (((i >> 2) & 1) << 13)];
            e0 += quad8(ps, A, D, 0);
        }
        // q=1: psi_i, i = std12*4 + std11*2 + std10 -> pos12, pos3, pos2
        {
            const int Fe = swz((r & 3) | (((r >> 2) & 1) << 13) |
                               (((r >> 3) & 15) << 4) | (((r >> 7) & 15) << 8));
            float ps[8];
#pragma unroll
            for (int i = 0; i < 8; ++i)
                ps[i] = st[Fe ^ ((i & 1) << 2) ^ (((i >> 1) & 1) << 3) ^ (((i >> 2) & 1) << 12)];
            e1 += quad8(ps, A, D, 1);
        }
    }

    // ---- block reduction ----
#pragma unroll
    for (int o = 32; o > 0; o >>= 1) {
        e0 += __shfl_down(e0, o);
        e1 += __shfl_down(e1, o);
    }
    if ((t & 63) == 0) {
        red[(t >> 6) * 2]     = e0;
        red[(t >> 6) * 2 + 1] = e1;
    }
    __syncthreads();
    if (t == 0) {
        float s0 = 0.0f, s1 = 0.0f;
#pragma unroll
        for (int i = 0; i < NT / 64; ++i) { s0 += red[i * 2]; s1 += red[i * 2 + 1]; }
        out[b * 2 + 0] = s0;
        out[b * 2 + 1] = s1;
    }
}

extern "C" void kernel_launch(void* const* d_in, const int* in_sizes, int n_in,
                              void* d_out, int out_size, void* d_ws, size_t ws_size,
                              hipStream_t stream) {
    const float* X  = (const float*)d_in[0];
    const float* TH = (const float*)d_in[1];
    const float* A  = (const float*)d_in[2];
    const float* Bc = (const float*)d_in[3];
    const float* D  = (const float*)d_in[4];
    float* out = (float*)d_out;
    vqc_kernel<<<512, NT, 0, stream>>>(X, TH, A, Bc, D, out);
}

// Round 7
// 63.459 us; speedup vs baseline: 1.1737x; 1.1737x over previous
//
#include <hip/hip_runtime.h>
#include <math.h>

#define NQ 14
#define NSTATE (1 << NQ)        // 16384
#define DEPTH  6
#define NT     1024             // 16 waves/block

// dword-index swizzle: XOR bits 6-8 into 2-4
__device__ __forceinline__ int swz(int n) { return n ^ ((n >> 4) & 28); }

// fused CNOT ladders (even after odd): m = sigma_e(sigma_o(n))
__device__ __forceinline__ int sigma(int n) {
    int m = n ^ ((n & 0x1554) >> 1);
    return m ^ ((m & 0x2AAA) >> 1);
}

// RY on psi-index bit JB over a 16-amp real register block
template <int JB>
__device__ __forceinline__ void ry16(float (&p)[16], float c, float s) {
#pragma unroll
    for (int i = 0; i < 16; ++i) {
        if (!((i >> JB) & 1)) {
            const int i1 = i | (1 << JB);
            float a0 = p[i], a1 = p[i1];
            p[i]  = c * a0 - s * a1;
            p[i1] = s * a0 + c * a1;
        }
    }
}

// RMW pass rotating the 4 amplitude-index bits at [SH, SH+4)
template <int SH, bool ROT01>
__device__ __forceinline__ void pass_rmw(float* st, int t,
                                         float c0, float s0, float c1, float s1,
                                         float c2, float s2, float c3, float s3) {
    const int n = (t & ((1 << SH) - 1)) | ((t >> SH) << (SH + 4));
    float p[16];
#pragma unroll
    for (int i = 0; i < 16; ++i) p[i] = st[swz(n | (i << SH))];
    if (ROT01) {
        ry16<0>(p, c0, s0);
        ry16<1>(p, c1, s1);
    }
    ry16<2>(p, c2, s2);
    ry16<3>(p, c3, s3);
#pragma unroll
    for (int i = 0; i < 16; ++i) st[swz(n | (i << SH))] = p[i];
    __syncthreads();
}

// CNOT-fused pass (layers k>=1): sigma maps aligned 16-blocks to aligned
// 16-blocks; read 4x float4 from source block, register-permute, rotate, write.
__device__ __forceinline__ void pass_cnot(float* st, int t,
                                          float c0, float s0, float c1, float s1,
                                          float c2, float s2, float c3, float s3) {
    const int bstart = sigma(t << 4) & ~15;
    float tmp[16];
#pragma unroll
    for (int g = 0; g < 4; ++g)
        *(float4*)&tmp[g * 4] = *(const float4*)&st[swz(bstart + g * 4)];
    const int t0 = t & 1;                        // n bit 4
    float p[16];
#pragma unroll
    for (int i = 0; i < 16; ++i) {
        const int i0 = i & 1, i1 = (i >> 1) & 1, i2 = (i >> 2) & 1, i3 = (i >> 3) & 1;
        const int s = (i0 ^ i1 ^ i2) | ((i1 ^ i2) << 1) | ((i2 ^ i3) << 2) | (i3 << 3);
        p[i] = t0 ? tmp[s ^ 12] : tmp[s];        // sigma_low(i) = s ^ (t0*12)
    }
    __syncthreads();                             // all reads before any write
    ry16<0>(p, c0, s0);
    ry16<1>(p, c1, s1);
    ry16<2>(p, c2, s2);
    ry16<3>(p, c3, s3);
#pragma unroll
    for (int g = 0; g < 4; ++g)
        *(float4*)&st[swz((t << 4) + g * 4)] = *(const float4*)&p[g * 4];
    __syncthreads();
}

__global__ __launch_bounds__(NT, 4)
void vqc_kernel(const float* __restrict__ X,    // (512,14)
                const float* __restrict__ TH,   // (6,14)
                const float* __restrict__ A,    // (14,28)
                const float* __restrict__ Bc,   // (14,28)  unused: state stays real
                const float* __restrict__ D,    // (14,8)
                float* __restrict__ out)        // (512,2)
{
    __shared__ __align__(16) float st[NSTATE];  // 64 KiB real state
    __shared__ float2 tb[DEPTH * NQ];           // (cos,sin) per theta
    __shared__ float2 xf[NQ];                   // (c-s, c+s) per amplitude bit j
    __shared__ float  red[2 * (NT / 64)];

    const int t = threadIdx.x;
    const int b = blockIdx.x;

    // ---- trig tables: computed once per block, read as LDS broadcasts ----
    if (t < DEPTH * NQ) {
        float s, c;
        __sincosf(0.5f * TH[t], &s, &c);
        tb[t] = make_float2(c, s);
    } else if (t < DEPTH * NQ + NQ) {
        const int j = t - DEPTH * NQ;           // amplitude-bit position j <-> wire 13-j
        float s, c;
        __sincosf(0.5f * X[b * NQ + (13 - j)], &s, &c);
        xf[j] = make_float2(c - s, c + s);
    }
    __syncthreads();

    // ---- layer 0 P1: product-state init evaluated at sigma(n), rotate bits 0-3 ----
    {
        const int mt = sigma(t << 4);
        float sh = 1.0f / 128.0f;               // product over mt bits 4..13
#pragma unroll
        for (int j = 4; j < 14; ++j) {
            float2 f = xf[j];
            sh *= ((mt >> j) & 1) ? f.y : f.x;
        }
        float fa[4], fb[4];                     // value at bit=mt_j, and flipped
#pragma unroll
        for (int j = 0; j < 4; ++j) {
            float2 f = xf[j];
            const int mj = (mt >> j) & 1;
            fa[j] = mj ? f.y : f.x;
            fb[j] = mj ? f.x : f.y;
        }
        float p[16];
#pragma unroll
        for (int i = 0; i < 16; ++i) {
            const int sl = sigma(i);            // compile-time per unrolled i
            float v = sh;
            v *= (sl & 1)        ? fb[0] : fa[0];
            v *= ((sl >> 1) & 1) ? fb[1] : fa[1];
            v *= ((sl >> 2) & 1) ? fb[2] : fa[2];
            v *= ((sl >> 3) & 1) ? fb[3] : fa[3];
            p[i] = v;
        }
        float2 q0 = tb[13], q1 = tb[12], q2 = tb[11], q3 = tb[10];
        ry16<0>(p, q0.x, q0.y);                 // amp bit 0 <-> wire 13
        ry16<1>(p, q1.x, q1.y);
        ry16<2>(p, q2.x, q2.y);
        ry16<3>(p, q3.x, q3.y);
#pragma unroll
        for (int g = 0; g < 4; ++g)
            *(float4*)&st[swz((t << 4) + g * 4)] =
                make_float4(p[4 * g], p[4 * g + 1], p[4 * g + 2], p[4 * g + 3]);
    }
    __syncthreads();

    // ---- layers ----
    for (int k = 0; k < DEPTH; ++k) {
        const float2* tbk = tb + k * NQ;
        if (k > 0) {                            // layer 0's P1 done above
            float2 q0 = tbk[13], q1 = tbk[12], q2 = tbk[11], q3 = tbk[10];
            pass_cnot(st, t, q0.x, q0.y, q1.x, q1.y, q2.x, q2.y, q3.x, q3.y);
        }
        {
            float2 q0 = tbk[9], q1 = tbk[8], q2 = tbk[7], q3 = tbk[6];
            pass_rmw<4, true>(st, t, q0.x, q0.y, q1.x, q1.y, q2.x, q2.y, q3.x, q3.y);
        }
        {
            float2 q0 = tbk[5], q1 = tbk[4], q2 = tbk[3], q3 = tbk[2];
            pass_rmw<8, true>(st, t, q0.x, q0.y, q1.x, q1.y, q2.x, q2.y, q3.x, q3.y);
        }
        {
            float2 q2 = tbk[1], q3 = tbk[0];    // bit 12 <-> wire 1, bit 13 <-> wire 0
            pass_rmw<10, false>(st, t, 1.f, 0.f, 1.f, 0.f, q2.x, q2.y, q3.x, q3.y);
        }
    }

    // ---- expectations (real state: B drops out) ----
    float e[2];
#pragma unroll
    for (int q = 0; q < 2; ++q) {
        const int shift = 11 - q;
        float dg[8];
#pragma unroll
        for (int i = 0; i < 7; ++i) dg[i] = 2.0f * D[q * 8 + i + 1];
        dg[7] = 0.0f;
        float acc = 0.0f;
        const int lowmask = (1 << shift) - 1;
        for (int r = t; r < NSTATE / 8; r += NT) {   // 2 iterations
            const int base = ((r >> shift) << (shift + 3)) | (r & lowmask);
            float ps[8];
#pragma unroll
            for (int i = 0; i < 8; ++i) ps[i] = st[swz(base + (i << shift))];
#pragma unroll
            for (int i = 0; i < 8; ++i) acc += dg[i] * ps[i] * ps[i];
            int kk = 0;
#pragma unroll
            for (int i = 1; i < 8; ++i)
#pragma unroll
                for (int j = 0; j < i; ++j, ++kk)
                    acc += 2.0f * A[q * 28 + kk] * ps[i] * ps[j];
        }
        e[q] = acc;
    }

    // ---- block reduction ----
    float v0 = e[0], v1 = e[1];
#pragma unroll
    for (int o = 32; o > 0; o >>= 1) {
        v0 += __shfl_down(v0, o);
        v1 += __shfl_down(v1, o);
    }
    if ((t & 63) == 0) {
        red[(t >> 6) * 2]     = v0;
        red[(t >> 6) * 2 + 1] = v1;
    }
    __syncthreads();
    if (t == 0) {
        float s0 = 0.0f, s1 = 0.0f;
#pragma unroll
        for (int i = 0; i < NT / 64; ++i) { s0 += red[i * 2]; s1 += red[i * 2 + 1]; }
        out[b * 2 + 0] = s0;
        out[b * 2 + 1] = s1;
    }
}

extern "C" void kernel_launch(void* const* d_in, const int* in_sizes, int n_in,
                              void* d_out, int out_size, void* d_ws, size_t ws_size,
                              hipStream_t stream) {
    const float* X  = (const float*)d_in[0];
    const float* TH = (const float*)d_in[1];
    const float* A  = (const float*)d_in[2];
    const float* Bc = (const float*)d_in[3];
    const float* D  = (const float*)d_in[4];
    float* out = (float*)d_out;
    vqc_kernel<<<512, NT, 0, stream>>>(X, TH, A, Bc, D, out);
}